// Round 21
// baseline (58.745 us; speedup 1.0000x reference)
//
#include <hip/hip_runtime.h>

// Legendre2 v20: STATIC-__shared__ co-residency probe (last structural
// hypothesis). All prior co-residency failures (R2/R6/R7/R8/R15, occupancy
// pinned ~19% from 40-140KB) used dynamic extern __shared__ +
// hipFuncSetAttribute; VGPR/LDS math says 2 blocks/CU should fit. This
// probe uses static __shared__ char[65536] (no attribute, no dynamic arg):
//   BH A-table 48K + 8x2KB scratch (scales aliased) = 64KB exactly;
//   C-frags in 16 registers (v15-verified); 2-phase epilogue transpose
//   (v15-verified). Inner loop = v19 (scaled recurrence, cvt_pkrtz z,
//   v2f32 pk-fma folds, cvt_pk_bf16 epilogue). Grid 512 x 512thr, each
//   wave 128 rows = 2 iters x 64 rows (2-tile B-frag sharing).
// Numerics identical to v19 -> absmax must stay 16777220.
// N=524288, D=64, K=64, O=32, DEGREE=6.

typedef _Float16 f16x8 __attribute__((ext_vector_type(8)));
typedef __fp16   h16x2 __attribute__((ext_vector_type(2)));
typedef short    s16x8 __attribute__((ext_vector_type(8)));
typedef float    f32x4 __attribute__((ext_vector_type(4)));
typedef float    f32x2 __attribute__((ext_vector_type(2)));
struct f32x2p { f32x2 lo, hi; };

#define NN      524288
#define BLOCKS  512
#define THREADS 512
#define NWAVES  8
#define NITER   2                        // 2 x 64-row (2-tile) passes per wave

// LDS byte offsets (static 64 KiB)
#define BH_OFF  0                        // 48 frags * 1 KB (f16 of A, scaled)
#define SCR_OFF 49152                    // 8 waves * 2 KB scratch (scales alias)

__device__ __forceinline__ unsigned short f2bf(float x) {
    unsigned u = __builtin_bit_cast(unsigned, x);
    return (unsigned short)((u + 0x7FFFu + ((u >> 16) & 1u)) >> 16);
}

__global__ __launch_bounds__(THREADS) void leg_mfma(
    const float* __restrict__ z, const float* __restrict__ T,
    const float* __restrict__ Cm, const float* __restrict__ beta,
    float* __restrict__ out)
{
    __shared__ char smem[65536];         // STATIC -- the probe variable
    float* scale_s = (float*)(smem + SCR_OFF);   // aliased; dead after staging
    const int tid  = (int)threadIdx.x;
    const int lane = tid & 63;
    const int wv   = tid >> 6;
    const int lrow = lane & 15;          // row (A-op) / col (C/D) index
    const int lhi  = lane >> 4;          // 0..3

    // ---------- C-operand frags -> REGISTERS (bf16, scaled by c6=5/16) ------
    s16x8 ch[2][2];
    #pragma unroll
    for (int s = 0; s < 2; ++s)
        #pragma unroll
        for (int fo = 0; fo < 2; ++fo) {
            const int o  = lrow + (fo << 4);
            const int k0 = (lhi << 3) + (s << 5);
            const float4 v0 = *(const float4*)(Cm + (size_t)o * 64 + k0);
            const float4 v1 = *(const float4*)(Cm + (size_t)o * 64 + k0 + 4);
            const float vv[8] = {v0.x, v0.y, v0.z, v0.w, v1.x, v1.y, v1.z, v1.w};
            s16x8 fr;
            #pragma unroll
            for (int j = 0; j < 8; ++j) fr[j] = (short)f2bf(vv[j] * 0.3125f);
            ch[s][fo] = fr;
        }

    // ---------- phase A: per-row scales with recurrence scaling folded in ---
    if (tid < 384) {
        const int mat = tid >> 6, kc = tid & 63;
        const float4* tr = (const float4*)(T + (size_t)((mat << 6) + kc) * 64);
        float s = 0.f;
        #pragma unroll
        for (int q = 0; q < 16; ++q) { float4 v = tr[q]; s += v.x + v.y + v.z + v.w; }
        const float smul[6] = {1.f, 3.f, 1.25f, 28.f / 9.f, 81.f / 64.f, 704.f / 225.f};
        const float sc = (mat == 0) ? 1.f : smul[mat] / s;
        scale_s[tid] = sc;
    }
    __syncthreads();

    // ---------- phase B: build B-operand frags of A (f16, scaled) -----------
    for (int g = tid; g < 3072; g += THREADS) {
        const int mat = g >> 9;
        const int s   = (g >> 8) & 1;
        const int f   = (g >> 6) & 3;
        const int l   = g & 63;
        const int kc  = (l & 15) + (f << 4);
        const int d0  = ((l >> 4) << 3) + (s << 5);
        const float sc = scale_s[(mat << 6) + kc];
        const float* src = T + (size_t)((mat << 6) + kc) * 64 + d0;
        const float4 v0 = *(const float4*)(src);
        const float4 v1 = *(const float4*)(src + 4);
        const float vv[8] = {v0.x, v0.y, v0.z, v0.w, v1.x, v1.y, v1.z, v1.w};
        f16x8 hi;
        #pragma unroll
        for (int j = 0; j < 8; ++j) hi[j] = (_Float16)(vv[j] * sc);
        const int fr = (((mat << 1) + s) << 2) + f;
        *(f16x8*)(smem + BH_OFF + fr * 1024 + l * 16) = hi;
    }
    __syncthreads();                     // scales dead; scratch owns region

    // ---------- main: each wave owns 128 rows, 2 iters of 64 rows -----------
    const int    gw      = blockIdx.x * NWAVES + wv;
    const size_t rowbase = (size_t)gw * 128;
    float* scr = (float*)(smem + SCR_OFF) + wv * 512;   // 16 rows x 32 f32

    const float beta0 = beta[lrow];
    const float beta1 = beta[16 + lrow];
    const f32x2 one2 = {1.f, 1.f};

    f16x8 zh[2][2][2];                   // [u][t][s]

    // one Legendre level (scaled): PT := a (.) PC - PT as v2f32 (pk fma)
    auto leg_step = [&](int mat, f32x4 (&PC)[2][2][4], f32x4 (&PT)[2][2][4]) {
        __builtin_amdgcn_s_setprio(1);
        #pragma unroll
        for (int f = 0; f < 4; ++f) {
            const int fr0 = mat * 8 + f;       // s=0
            const int fr1 = mat * 8 + 4 + f;   // s=1
            const f16x8 bh0 = *(const f16x8*)(smem + BH_OFF + fr0 * 1024 + lane * 16);
            const f16x8 bh1 = *(const f16x8*)(smem + BH_OFF + fr1 * 1024 + lane * 16);
            #pragma unroll
            for (int u = 0; u < 2; ++u)
                #pragma unroll
                for (int t = 0; t < 2; ++t) {
                    f32x4 a = {0.f, 0.f, 0.f, 0.f};
                    a = __builtin_amdgcn_mfma_f32_16x16x32_f16(zh[u][t][0], bh0, a, 0, 0, 0);
                    a = __builtin_amdgcn_mfma_f32_16x16x32_f16(zh[u][t][1], bh1, a, 0, 0, 0);
                    f32x2p av = __builtin_bit_cast(f32x2p, a);
                    f32x2p pc = __builtin_bit_cast(f32x2p, PC[u][t][f]);
                    f32x2p pt = __builtin_bit_cast(f32x2p, PT[u][t][f]);
                    pt.lo = av.lo * pc.lo - pt.lo;
                    pt.hi = av.hi * pc.hi - pt.hi;
                    PT[u][t][f] = __builtin_bit_cast(f32x4, pt);
                }
        }
        __builtin_amdgcn_s_setprio(0);
    };

    for (int it = 0; it < NITER; ++it) {
        // load + convert z (packed RTZ)
        #pragma unroll
        for (int u = 0; u < 2; ++u)
            #pragma unroll
            for (int t = 0; t < 2; ++t)
                #pragma unroll
                for (int s = 0; s < 2; ++s) {
                    const float* p = z + (rowbase + (size_t)it * 64 + u * 32 + t * 16 + lrow) * 64
                                       + (s << 5) + (lhi << 3);
                    const float4 q0 = *(const float4*)(p);
                    const float4 q1 = *(const float4*)(p + 4);
                    union { f16x8 v; h16x2 h[4]; } uz;
                    uz.h[0] = __builtin_amdgcn_cvt_pkrtz(q0.x, q0.y);
                    uz.h[1] = __builtin_amdgcn_cvt_pkrtz(q0.z, q0.w);
                    uz.h[2] = __builtin_amdgcn_cvt_pkrtz(q1.x, q1.y);
                    uz.h[3] = __builtin_amdgcn_cvt_pkrtz(q1.z, q1.w);
                    zh[u][t][s] = uz.v;
                }

        // Scaled Legendre chain: pA = Q1, pB = Q2, ping-pong; Q6 ends in pB
        f32x4 pA[2][2][4], pB[2][2][4];
        __builtin_amdgcn_s_setprio(1);
        #pragma unroll
        for (int f = 0; f < 4; ++f) {
            const int fr0 = f, fr1 = 4 + f;
            const f16x8 bh0 = *(const f16x8*)(smem + BH_OFF + fr0 * 1024 + lane * 16);
            const f16x8 bh1 = *(const f16x8*)(smem + BH_OFF + fr1 * 1024 + lane * 16);
            #pragma unroll
            for (int u = 0; u < 2; ++u)
                #pragma unroll
                for (int t = 0; t < 2; ++t) {
                    f32x4 a = {0.f, 0.f, 0.f, 0.f};
                    a = __builtin_amdgcn_mfma_f32_16x16x32_f16(zh[u][t][0], bh0, a, 0, 0, 0);
                    a = __builtin_amdgcn_mfma_f32_16x16x32_f16(zh[u][t][1], bh1, a, 0, 0, 0);
                    pA[u][t][f] = a;
                }
        }
        #pragma unroll
        for (int f = 0; f < 4; ++f) {
            const int fr0 = 8 + f, fr1 = 12 + f;
            const f16x8 bh0 = *(const f16x8*)(smem + BH_OFF + fr0 * 1024 + lane * 16);
            const f16x8 bh1 = *(const f16x8*)(smem + BH_OFF + fr1 * 1024 + lane * 16);
            #pragma unroll
            for (int u = 0; u < 2; ++u)
                #pragma unroll
                for (int t = 0; t < 2; ++t) {
                    f32x4 a = {0.f, 0.f, 0.f, 0.f};
                    a = __builtin_amdgcn_mfma_f32_16x16x32_f16(zh[u][t][0], bh0, a, 0, 0, 0);
                    a = __builtin_amdgcn_mfma_f32_16x16x32_f16(zh[u][t][1], bh1, a, 0, 0, 0);
                    f32x2p av = __builtin_bit_cast(f32x2p, a);
                    f32x2p pa = __builtin_bit_cast(f32x2p, pA[u][t][f]);
                    f32x2p pb;
                    pb.lo = av.lo * pa.lo - one2;
                    pb.hi = av.hi * pa.hi - one2;
                    pB[u][t][f] = __builtin_bit_cast(f32x4, pb);
                }
        }
        __builtin_amdgcn_s_setprio(0);
        leg_step(2, pB, pA);   // Q3
        leg_step(3, pA, pB);   // Q4
        leg_step(4, pB, pA);   // Q5
        leg_step(5, pA, pB);   // Q6 = pB

        // ---------------- epilogue: out = Q6 @ (c6*C)^T + beta --------------
        // transpose in two k-32 phases through 16x32 scratch (v15-verified)
        #pragma unroll
        for (int u = 0; u < 2; ++u)
            #pragma unroll
            for (int t = 0; t < 2; ++t) {
                s16x8 p6h[2];
                #pragma unroll
                for (int s = 0; s < 2; ++s) {
                    #pragma unroll
                    for (int f_ = 0; f_ < 2; ++f_) {
                        const int f    = 2 * s + f_;
                        const int colp = (f_ << 4) + lrow;
                        #pragma unroll
                        for (int r = 0; r < 4; ++r) {
                            const int row = lhi * 4 + r;
                            const int g4  = ((colp >> 2) ^ row) & 7;
                            scr[row * 32 + g4 * 4 + (colp & 3)] = pB[u][t][f][r];
                        }
                    }
                    float vv[8];
                    #pragma unroll
                    for (int jg = 0; jg < 2; ++jg) {
                        const int g4r = (((lhi << 1) + jg) ^ lrow) & 7;
                        const float4 q = *(const float4*)(scr + lrow * 32 + g4r * 4);
                        vv[jg * 4 + 0] = q.x; vv[jg * 4 + 1] = q.y;
                        vv[jg * 4 + 2] = q.z; vv[jg * 4 + 3] = q.w;
                    }
                    union { s16x8 v; unsigned w[4]; } ph;
                    #pragma unroll
                    for (int m = 0; m < 4; ++m)
                        asm("v_cvt_pk_bf16_f32 %0, %1, %2"
                            : "=v"(ph.w[m]) : "v"(vv[2 * m]), "v"(vv[2 * m + 1]));
                    p6h[s] = ph.v;
                }
                #pragma unroll
                for (int fo = 0; fo < 2; ++fo) {
                    f32x4 o = {0.f, 0.f, 0.f, 0.f};
                    o = __builtin_amdgcn_mfma_f32_16x16x32_bf16(p6h[0], ch[0][fo], o, 0, 0, 0);
                    o = __builtin_amdgcn_mfma_f32_16x16x32_bf16(p6h[1], ch[1][fo], o, 0, 0, 0);
                    const float bb = fo ? beta1 : beta0;
                    const size_t r0 = rowbase + (size_t)it * 64 + u * 32 + t * 16 + lhi * 4;
                    #pragma unroll
                    for (int r = 0; r < 4; ++r)
                        out[(r0 + r) * 32 + (fo << 4) + lrow] = o[r] + bb;
                }
            }
    }
}

extern "C" void kernel_launch(void* const* d_in, const int* in_sizes, int n_in,
                              void* d_out, int out_size, void* d_ws, size_t ws_size,
                              hipStream_t stream) {
    const float* z    = (const float*)d_in[0];
    const float* T    = (const float*)d_in[1];
    const float* C    = (const float*)d_in[2];
    const float* beta = (const float*)d_in[3];
    float* out = (float*)d_out;
    (void)in_sizes; (void)n_in; (void)out_size; (void)d_ws; (void)ws_size;

    // NOTE: static __shared__, no hipFuncSetAttribute, no dynamic LDS arg.
    leg_mfma<<<BLOCKS, THREADS, 0, stream>>>(z, T, C, beta, out);
}

// Round 22
// 47.269 us; speedup vs baseline: 1.2428x; 1.2428x over previous
//
#include <hip/hip_runtime.h>

// Legendre2 FINAL (= v17b, session best 47.3us, R18-verified).
//  - Split-precision MFMA: z and A in f16 (single term), f32 accumulate;
//    chained k-half MFMA (2 per 16x16 tile per level).
//  - SCALED RECURRENCE: Q_i = P_i/c_i (c_i = b_i*c_{i-2}) makes each fold a
//    single fma: Q_i = a (.) Q_{i-1} - Q_{i-2}; level scales folded into the
//    f16 A-table (x1, x3, x5/4, x28/9, x81/64, x704/225 incl. coef/rowsum),
//    c_6 = 5/16 folded into bf16 C.
//  - cvt_pkrtz packed f32->f16 z-conversion.
//  - 2-tile (64-row) B-frag sharing per wave-iter; setprio(1) on MFMA
//    clusters; single-term bf16 epilogue via XOR-swizzled LDS transpose.
//  - 256 blocks x 512 thr (the only clean-codegen point: VGPR 128, zero
//    spill); 8 waves x 256 rows; full 48 KB A-table staged once per block.
// Session structural findings: 1 block/CU is platform-pinned regardless of
// LDS size/mechanism (7 probes); kernel time = sum of pipe busy times at
// 2 waves/SIMD; VALU was the last convertible pipe (exhausted at R20).
// N=524288, D=64, K=64, O=32, DEGREE=6.

typedef _Float16 f16x8 __attribute__((ext_vector_type(8)));
typedef __fp16   h16x2 __attribute__((ext_vector_type(2)));
typedef short    s16x8 __attribute__((ext_vector_type(8)));
typedef float    f32x4 __attribute__((ext_vector_type(4)));

#define NN      524288
#define BLOCKS  256
#define THREADS 512
#define NWAVES  8
#define NITER   4                        // 4 x 64-row (2-tile) passes per wave

// LDS byte offsets
#define BH_OFF    0                      // 48 frags * 1 KB (f16 of A, scaled)
#define CF_OFF    49152                  // 4 frags * 1 KB (bf16 of c6*C)
#define SCALE_OFF 53248                  // 384 f32 scales
#define SCR_OFF   54784                  // 8 waves * 4 KB transpose scratch
#define SMEM_BYTES (SCR_OFF + NWAVES * 4096)   // 87552 B

__device__ __forceinline__ unsigned short f2bf(float x) {
    unsigned u = __builtin_bit_cast(unsigned, x);
    return (unsigned short)((u + 0x7FFFu + ((u >> 16) & 1u)) >> 16);
}

__global__ __launch_bounds__(THREADS) void leg_mfma(
    const float* __restrict__ z, const float* __restrict__ T,
    const float* __restrict__ Cm, const float* __restrict__ beta,
    float* __restrict__ out)
{
    extern __shared__ char smem[];
    float* scale_s = (float*)(smem + SCALE_OFF);
    const int tid  = (int)threadIdx.x;
    const int lane = tid & 63;
    const int wv   = tid >> 6;
    const int lrow = lane & 15;          // row (A-op) / col (C/D) index
    const int lhi  = lane >> 4;          // 0..3

    // ---------- phase A: per-row scales with recurrence scaling folded in ---
    // smul[i] = coef_i * s_i (s_i = c_{i-1}/c_i).
    if (tid < 384) {
        const int mat = tid >> 6, kc = tid & 63;
        const float4* tr = (const float4*)(T + (size_t)((mat << 6) + kc) * 64);
        float s = 0.f;
        #pragma unroll
        for (int q = 0; q < 16; ++q) { float4 v = tr[q]; s += v.x + v.y + v.z + v.w; }
        const float smul[6] = {1.f, 3.f, 1.25f, 28.f / 9.f, 81.f / 64.f, 704.f / 225.f};
        const float sc = (mat == 0) ? 1.f : smul[mat] / s;
        scale_s[tid] = sc;
    }
    __syncthreads();

    // ---------- phase B: build B-operand frags of A (f16, scaled) -----------
    for (int g = tid; g < 3072; g += THREADS) {
        const int mat = g >> 9;
        const int s   = (g >> 8) & 1;
        const int f   = (g >> 6) & 3;
        const int l   = g & 63;
        const int kc  = (l & 15) + (f << 4);
        const int d0  = ((l >> 4) << 3) + (s << 5);
        const float sc = scale_s[(mat << 6) + kc];
        const float* src = T + (size_t)((mat << 6) + kc) * 64 + d0;
        const float4 v0 = *(const float4*)(src);
        const float4 v1 = *(const float4*)(src + 4);
        const float vv[8] = {v0.x, v0.y, v0.z, v0.w, v1.x, v1.y, v1.z, v1.w};
        f16x8 hi;
        #pragma unroll
        for (int j = 0; j < 8; ++j) hi[j] = (_Float16)(vv[j] * sc);
        const int fr = (((mat << 1) + s) << 2) + f;
        *(f16x8*)(smem + BH_OFF + fr * 1024 + l * 16) = hi;
    }
    // C-operand frags (bf16, scaled by c6 = 5/16)
    if (tid < 256) {
        const int s  = (tid >> 7) & 1;
        const int fo = (tid >> 6) & 1;
        const int l  = tid & 63;
        const int o  = (l & 15) + (fo << 4);
        const int k0 = ((l >> 4) << 3) + (s << 5);
        const float* src = Cm + (size_t)o * 64 + k0;
        const float4 v0 = *(const float4*)src;
        const float4 v1 = *(const float4*)(src + 4);
        const float vv[8] = {v0.x, v0.y, v0.z, v0.w, v1.x, v1.y, v1.z, v1.w};
        s16x8 fr;
        #pragma unroll
        for (int j = 0; j < 8; ++j) fr[j] = (short)f2bf(vv[j] * 0.3125f);
        *(s16x8*)(smem + CF_OFF + ((s << 1) + fo) * 1024 + l * 16) = fr;
    }
    __syncthreads();

    // ---------- main: each wave owns 256 rows, 4 iters of 64 rows -----------
    const int    gw      = blockIdx.x * NWAVES + wv;
    const size_t rowbase = (size_t)gw * 256;
    float* scr = (float*)(smem + SCR_OFF + wv * 4096);

    const float beta0 = beta[lrow];
    const float beta1 = beta[16 + lrow];

    f16x8 zh[2][2][2];                   // [u][t][s]

    // one Legendre level (scaled): PT := a (.) PC - PT  (single fma)
    auto leg_step = [&](int mat, f32x4 (&PC)[2][2][4], f32x4 (&PT)[2][2][4]) {
        __builtin_amdgcn_s_setprio(1);
        #pragma unroll
        for (int f = 0; f < 4; ++f) {
            const int fr0 = mat * 8 + f;       // s=0
            const int fr1 = mat * 8 + 4 + f;   // s=1
            const f16x8 bh0 = *(const f16x8*)(smem + BH_OFF + fr0 * 1024 + lane * 16);
            const f16x8 bh1 = *(const f16x8*)(smem + BH_OFF + fr1 * 1024 + lane * 16);
            #pragma unroll
            for (int u = 0; u < 2; ++u)
                #pragma unroll
                for (int t = 0; t < 2; ++t) {
                    f32x4 a = {0.f, 0.f, 0.f, 0.f};
                    a = __builtin_amdgcn_mfma_f32_16x16x32_f16(zh[u][t][0], bh0, a, 0, 0, 0);
                    a = __builtin_amdgcn_mfma_f32_16x16x32_f16(zh[u][t][1], bh1, a, 0, 0, 0);
                    #pragma unroll
                    for (int r = 0; r < 4; ++r)
                        PT[u][t][f][r] = a[r] * PC[u][t][f][r] - PT[u][t][f][r];
                }
        }
        __builtin_amdgcn_s_setprio(0);
    };

    for (int it = 0; it < NITER; ++it) {
        // load + convert z (packed RTZ: 4 cvt_pkrtz per 8 elems)
        #pragma unroll
        for (int u = 0; u < 2; ++u)
            #pragma unroll
            for (int t = 0; t < 2; ++t)
                #pragma unroll
                for (int s = 0; s < 2; ++s) {
                    const float* p = z + (rowbase + (size_t)it * 64 + u * 32 + t * 16 + lrow) * 64
                                       + (s << 5) + (lhi << 3);
                    const float4 q0 = *(const float4*)(p);
                    const float4 q1 = *(const float4*)(p + 4);
                    union { f16x8 v; h16x2 h[4]; } uz;
                    uz.h[0] = __builtin_amdgcn_cvt_pkrtz(q0.x, q0.y);
                    uz.h[1] = __builtin_amdgcn_cvt_pkrtz(q0.z, q0.w);
                    uz.h[2] = __builtin_amdgcn_cvt_pkrtz(q1.x, q1.y);
                    uz.h[3] = __builtin_amdgcn_cvt_pkrtz(q1.z, q1.w);
                    zh[u][t][s] = uz.v;
                }

        // Scaled Legendre chain: pA = Q1, pB = Q2, ping-pong; Q6 ends in pB
        f32x4 pA[2][2][4], pB[2][2][4];
        // mat 0 -> pA  (Q1), chained
        __builtin_amdgcn_s_setprio(1);
        #pragma unroll
        for (int f = 0; f < 4; ++f) {
            const int fr0 = f, fr1 = 4 + f;
            const f16x8 bh0 = *(const f16x8*)(smem + BH_OFF + fr0 * 1024 + lane * 16);
            const f16x8 bh1 = *(const f16x8*)(smem + BH_OFF + fr1 * 1024 + lane * 16);
            #pragma unroll
            for (int u = 0; u < 2; ++u)
                #pragma unroll
                for (int t = 0; t < 2; ++t) {
                    f32x4 a = {0.f, 0.f, 0.f, 0.f};
                    a = __builtin_amdgcn_mfma_f32_16x16x32_f16(zh[u][t][0], bh0, a, 0, 0, 0);
                    a = __builtin_amdgcn_mfma_f32_16x16x32_f16(zh[u][t][1], bh1, a, 0, 0, 0);
                    pA[u][t][f] = a;
                }
        }
        // mat 1 -> pB = Q2 = a (.) Q1 - 1  (Q0 = ones)
        #pragma unroll
        for (int f = 0; f < 4; ++f) {
            const int fr0 = 8 + f, fr1 = 12 + f;
            const f16x8 bh0 = *(const f16x8*)(smem + BH_OFF + fr0 * 1024 + lane * 16);
            const f16x8 bh1 = *(const f16x8*)(smem + BH_OFF + fr1 * 1024 + lane * 16);
            #pragma unroll
            for (int u = 0; u < 2; ++u)
                #pragma unroll
                for (int t = 0; t < 2; ++t) {
                    f32x4 a = {0.f, 0.f, 0.f, 0.f};
                    a = __builtin_amdgcn_mfma_f32_16x16x32_f16(zh[u][t][0], bh0, a, 0, 0, 0);
                    a = __builtin_amdgcn_mfma_f32_16x16x32_f16(zh[u][t][1], bh1, a, 0, 0, 0);
                    #pragma unroll
                    for (int r = 0; r < 4; ++r)
                        pB[u][t][f][r] = a[r] * pA[u][t][f][r] - 1.0f;
                }
        }
        __builtin_amdgcn_s_setprio(0);
        leg_step(2, pB, pA);   // Q3
        leg_step(3, pA, pB);   // Q4
        leg_step(4, pB, pA);   // Q5
        leg_step(5, pA, pB);   // Q6 = pB

        // ---------------- epilogue: out = Q6 @ (c6*C)^T + beta --------------
        s16x8 ch[2][2];   // [s][fo]
        #pragma unroll
        for (int s = 0; s < 2; ++s)
            #pragma unroll
            for (int fo = 0; fo < 2; ++fo)
                ch[s][fo] = *(const s16x8*)(smem + CF_OFF + ((s << 1) + fo) * 1024 + lane * 16);
        #pragma unroll
        for (int u = 0; u < 2; ++u)
            #pragma unroll
            for (int t = 0; t < 2; ++t) {
                // transpose Q6 (C/D layout) -> A-op layout via XOR-swizzled scratch
                #pragma unroll
                for (int f = 0; f < 4; ++f)
                    #pragma unroll
                    for (int r = 0; r < 4; ++r) {
                        const int row = lhi * 4 + r;
                        const int k   = (f << 4) + lrow;
                        const int g4  = (k >> 2) ^ row;        // group swizzle
                        scr[row * 64 + g4 * 4 + (k & 3)] = pB[u][t][f][r];
                    }
                s16x8 p6h[2];
                #pragma unroll
                for (int s = 0; s < 2; ++s) {
                    const int g0 = lhi * 2 + s * 8;
                    const float4 q0 = *(const float4*)(scr + lrow * 64 + ((g0)     ^ lrow) * 4);
                    const float4 q1 = *(const float4*)(scr + lrow * 64 + ((g0 + 1) ^ lrow) * 4);
                    const float vv[8] = {q0.x, q0.y, q0.z, q0.w, q1.x, q1.y, q1.z, q1.w};
                    #pragma unroll
                    for (int j = 0; j < 8; ++j) p6h[s][j] = (short)f2bf(vv[j]);
                }
                #pragma unroll
                for (int fo = 0; fo < 2; ++fo) {
                    f32x4 o = {0.f, 0.f, 0.f, 0.f};
                    o = __builtin_amdgcn_mfma_f32_16x16x32_bf16(p6h[0], ch[0][fo], o, 0, 0, 0);
                    o = __builtin_amdgcn_mfma_f32_16x16x32_bf16(p6h[1], ch[1][fo], o, 0, 0, 0);
                    const float bb = fo ? beta1 : beta0;
                    const size_t r0 = rowbase + (size_t)it * 64 + u * 32 + t * 16 + lhi * 4;
                    #pragma unroll
                    for (int r = 0; r < 4; ++r)
                        out[(r0 + r) * 32 + (fo << 4) + lrow] = o[r] + bb;
                }
            }
    }
}

extern "C" void kernel_launch(void* const* d_in, const int* in_sizes, int n_in,
                              void* d_out, int out_size, void* d_ws, size_t ws_size,
                              hipStream_t stream) {
    const float* z    = (const float*)d_in[0];
    const float* T    = (const float*)d_in[1];
    const float* C    = (const float*)d_in[2];
    const float* beta = (const float*)d_in[3];
    float* out = (float*)d_out;
    (void)in_sizes; (void)n_in; (void)out_size; (void)d_ws; (void)ws_size;

    hipFuncSetAttribute((const void*)leg_mfma,
                        hipFuncAttributeMaxDynamicSharedMemorySize, SMEM_BYTES);
    leg_mfma<<<BLOCKS, THREADS, SMEM_BYTES, stream>>>(z, T, C, beta, out);
}